// Round 3
// baseline (467.609 us; speedup 1.0000x reference)
//
#include <hip/hip_runtime.h>
#include <cstdint>
#include <cstddef>

#define B_ 16
#define S_ 64
#define T_ 4096
#define C_ 512
#define H_ 8

// ws layout (float offsets):
#define WS_QKT     0         // [512][8]
#define WS_QB      4096      // [8]
#define WS_MS      8192      // [1024][8]
#define WS_LI      16384     // [1024][8]
#define WS_ATT     24576     // [B][H][T]  (524288)
#define WS_WSUM    548864    // [1024][8][512] (4194304)
#define WS_ATTNOUT 4743168   // [1024][512]   (524288)
// total 5267456 floats ~= 20.1 MB

// K1: q = Wq@x + bq; qh = q/8; qkT[c][h] = sum_d qh[h,d]*Wk[h*64+d, c];
// grid (8 c-slices, 8 h). qh computed redundantly per c-slice (cheap).
__global__ void k_prep(const float* __restrict__ x, const float* __restrict__ Wq,
                       const float* __restrict__ bq, const float* __restrict__ Wk,
                       const float* __restrict__ bk, float* __restrict__ qkT,
                       float* __restrict__ qb) {
  __shared__ float xs[C_];
  __shared__ float part[4][64];
  __shared__ float qh[64];
  int tid = threadIdx.x;
  int cs = blockIdx.x, h = blockIdx.y;
  xs[tid] = x[tid];
  xs[tid + 256] = x[tid + 256];
  __syncthreads();
  int d = tid & 63, pp = tid >> 6;
  const float* wrow = Wq + (size_t)(h * 64 + d) * C_ + pp * 128;
  const float* xp = xs + pp * 128;
  float s = 0.f;
#pragma unroll 4
  for (int c = 0; c < 128; ++c) s += wrow[c] * xp[c];
  part[pp][d] = s;
  __syncthreads();
  if (tid < 64) {
    float qv = part[0][tid] + part[1][tid] + part[2][tid] + part[3][tid] +
               bq[h * 64 + tid];
    qh[tid] = qv * 0.125f;  // * 1/sqrt(D)
  }
  __syncthreads();
  if (cs == 0 && tid == 0) {
    float sb = 0.f;
    for (int dd = 0; dd < 64; ++dd) sb += qh[dd] * bk[h * 64 + dd];
    qb[h] = sb;
  }
  if (tid < 64) {
    int c = cs * 64 + tid;
    float s2 = 0.f;
#pragma unroll 8
    for (int dd = 0; dd < 64; ++dd)
      s2 += qh[dd] * Wk[(size_t)(h * 64 + dd) * C_ + c];
    qkT[c * 8 + h] = s2;
  }
}

// K2: att[b][h][t] = qb[h] + sum_c qkT[c][h]*eh[b][c][t]
// grid (64, 16), block 256: 64 t per block, 4 c-slices of 128.
// qk reads are wave-uniform -> scalar (s_load) via readfirstlane.
__global__ __launch_bounds__(256, 4) void k_att(
    const float* __restrict__ eh, const float* __restrict__ qkT,
    const float* __restrict__ qb, float* __restrict__ att) {
  __shared__ float part[4 * 8 * 64];  // [cg][h][tl]
  int tid = threadIdx.x;
  int tl = tid & 63;
  int cg = __builtin_amdgcn_readfirstlane(tid >> 6);
  int b = blockIdx.y;
  int t0 = blockIdx.x * 64;
  const float* ehp = eh + ((size_t)b * C_ + (size_t)cg * 128) * T_ + t0 + tl;
  const float* qp = qkT + (size_t)cg * 128 * 8;
  float acc[8];
#pragma unroll
  for (int h = 0; h < 8; ++h) acc[h] = 0.f;
#pragma unroll 4
  for (int j = 0; j < 128; ++j) {
    float e = ehp[(size_t)j * T_];
    acc[0] += qp[j * 8 + 0] * e; acc[1] += qp[j * 8 + 1] * e;
    acc[2] += qp[j * 8 + 2] * e; acc[3] += qp[j * 8 + 3] * e;
    acc[4] += qp[j * 8 + 4] * e; acc[5] += qp[j * 8 + 5] * e;
    acc[6] += qp[j * 8 + 6] * e; acc[7] += qp[j * 8 + 7] * e;
  }
#pragma unroll
  for (int h = 0; h < 8; ++h) part[(cg * 8 + h) * 64 + tl] = acc[h];
  __syncthreads();
#pragma unroll
  for (int i = 0; i < 2; ++i) {
    int idx = tid + i * 256;
    int h = idx >> 6, tt = idx & 63;
    float v = part[(0 * 8 + h) * 64 + tt] + part[(1 * 8 + h) * 64 + tt] +
              part[(2 * 8 + h) * 64 + tt] + part[(3 * 8 + h) * 64 + tt] + qb[h];
    att[((size_t)b * H_ + h) * T_ + t0 + tt] = v;
  }
}

// K3: softmax stats per (n, h): ms = max, li = 1/sum(exp). grid 1024.
__global__ void k_stats(const float* __restrict__ att,
                        const int* __restrict__ starts,
                        const int* __restrict__ ends, float* __restrict__ ms,
                        float* __restrict__ li) {
  int tid = threadIdx.x;
  int n = blockIdx.x;
  int b = n >> 6;
  int start = starts[n], end = ends[n];
  int h = tid >> 5, tl = tid & 31;
  const float* ah = att + ((size_t)b * H_ + h) * T_;
  float mloc = -3.0e38f;
  for (int t = start + tl; t < end; t += 32) mloc = fmaxf(mloc, ah[t]);
#pragma unroll
  for (int off = 16; off > 0; off >>= 1)
    mloc = fmaxf(mloc, __shfl_xor(mloc, off, 32));
  float lloc = 0.f;
  for (int t = start + tl; t < end; t += 32) lloc += __expf(ah[t] - mloc);
#pragma unroll
  for (int off = 16; off > 0; off >>= 1) lloc += __shfl_xor(lloc, off, 32);
  if (tl == 0) { ms[n * 8 + h] = mloc; li[n * 8 + h] = 1.f / lloc; }
}

// K4: window-owned wsum. grid (64 windows, 16 b), block 256.
// Each block owns aligned t-window [w0, w0+64) of batch b; handles every
// segment intersecting it. Thread owns c0=tid, c1=tid+256.
// Whole-inside segments: plain store. Crossing segments: atomicAdd
// (wsum pre-zeroed by hipMemsetAsync).
__global__ __launch_bounds__(256, 4) void k_wsum_win(
    const float* __restrict__ eh, const float* __restrict__ att,
    const float* __restrict__ ms, const float* __restrict__ li,
    const int* __restrict__ starts, const int* __restrict__ ends,
    float* __restrict__ wsum) {
  __shared__ float pl[8 * 64];
  __shared__ int sseg[64], eseg[64];
  int tid = threadIdx.x;
  int b = blockIdx.y;
  int w0 = blockIdx.x * 64;
  if (tid < 64) {
    sseg[tid] = starts[b * 64 + tid];
    eseg[tid] = ends[b * 64 + tid];
  }
  __syncthreads();
  // qualifying segments form a contiguous range (starts/ends nondecreasing)
  int slo = 64, shi = 0;
  for (int s = 0; s < 64; ++s) {
    if (eseg[s] > w0 && sseg[s] < w0 + 64) {
      if (s < slo) slo = s;
      shi = s + 1;
    }
  }
  const float* e0p = eh + ((size_t)b * C_ + tid) * T_ + w0;
  const float* e1p = e0p + (size_t)256 * T_;
  for (int s = slo; s < shi; ++s) {
    int n = b * 64 + s;
    int st = sseg[s], en = eseg[s];
    int Ilo = st > w0 ? st : w0;
    int Ihi = en < w0 + 64 ? en : w0 + 64;
    // stage p[h][tl] for the window (0 outside [Ilo, Ihi))
#pragma unroll
    for (int i = 0; i < 2; ++i) {
      int idx = tid + i * 256;
      int h = idx >> 6;
      int t = w0 + (idx & 63);
      float pv = 0.f;
      if (t >= Ilo && t < Ihi)
        pv = __expf(att[((size_t)b * H_ + h) * T_ + t] - ms[n * 8 + h]) *
             li[n * 8 + h];
      pl[idx] = pv;
    }
    __syncthreads();
    float acc0[8], acc1[8];
#pragma unroll
    for (int h = 0; h < 8; ++h) { acc0[h] = 0.f; acc1[h] = 0.f; }
    int jlo = (Ilo - w0) & ~3, jhi = Ihi - w0;
    for (int j = jlo; j < jhi; j += 4) {
      float4 e0 = *(const float4*)(e0p + j);
      float4 e1 = *(const float4*)(e1p + j);
#pragma unroll
      for (int h = 0; h < 8; ++h) {
        const float4 p = *(const float4*)&pl[h * 64 + j];
        acc0[h] += p.x * e0.x + p.y * e0.y + p.z * e0.z + p.w * e0.w;
        acc1[h] += p.x * e1.x + p.y * e1.y + p.z * e1.z + p.w * e1.w;
      }
    }
    float* wp = wsum + (size_t)n * (H_ * C_);
    bool inner = (st >= w0) && (en <= w0 + 64);
    if (inner) {
#pragma unroll
      for (int h = 0; h < 8; ++h) {
        wp[h * C_ + tid] = acc0[h];
        wp[h * C_ + 256 + tid] = acc1[h];
      }
    } else {
#pragma unroll
      for (int h = 0; h < 8; ++h) {
        atomicAdd(&wp[h * C_ + tid], acc0[h]);
        atomicAdd(&wp[h * C_ + 256 + tid], acc1[h]);
      }
    }
    __syncthreads();
  }
}

// K5/K6: C[n][j] = sum_k A[n*aStride + (j/64)*aColPerH + k] * W[j*512+k]
//        + bias[j].  Block: 64 n x 32 j; lanes own n; weights via s_load.
__global__ __launch_bounds__(256, 4) void k_gemm(
    const float* __restrict__ A, int aStride, int aColPerH,
    const float* __restrict__ W, const float* __restrict__ bias,
    float* __restrict__ Cc) {
  __shared__ float As[64 * 65];  // [k][n], k-chunk of 64
  __shared__ float Cs[64 * 33];
  int tid = threadIdx.x;
  int lane = tid & 63;
  int wv = __builtin_amdgcn_readfirstlane(tid >> 6);
  int n0 = blockIdx.x * 64, j0 = blockIdx.y * 32;
  const float* Ab = A + (size_t)n0 * aStride + (size_t)(j0 >> 6) * aColPerH;
  const float* Wb = W + (size_t)(j0 + wv * 8) * C_;
  float acc[8];
#pragma unroll
  for (int jj = 0; jj < 8; ++jj) acc[jj] = 0.f;
  int sn = tid >> 4, sk = (tid & 15) * 4;
  for (int k0 = 0; k0 < 512; k0 += 64) {
#pragma unroll
    for (int r = 0; r < 4; ++r) {
      int nn = r * 16 + sn;
      float4 a = *(const float4*)&Ab[(size_t)nn * aStride + k0 + sk];
      As[(sk + 0) * 65 + nn] = a.x;
      As[(sk + 1) * 65 + nn] = a.y;
      As[(sk + 2) * 65 + nn] = a.z;
      As[(sk + 3) * 65 + nn] = a.w;
    }
    __syncthreads();
#pragma unroll 4
    for (int kk = 0; kk < 64; kk += 4) {
      float a0 = As[(kk + 0) * 65 + lane];
      float a1 = As[(kk + 1) * 65 + lane];
      float a2 = As[(kk + 2) * 65 + lane];
      float a3 = As[(kk + 3) * 65 + lane];
      const float* wr = Wb + k0 + kk;
#pragma unroll
      for (int jj = 0; jj < 8; ++jj) {
        const float* w4 = wr + (size_t)jj * C_;
        acc[jj] += w4[0] * a0 + w4[1] * a1 + w4[2] * a2 + w4[3] * a3;
      }
    }
    __syncthreads();
  }
#pragma unroll
  for (int jj = 0; jj < 8; ++jj) Cs[lane * 33 + wv * 8 + jj] = acc[jj];
  __syncthreads();
#pragma unroll
  for (int r = 0; r < 2; ++r) {
    int idx = tid + r * 256;
    int n = idx >> 3, j4 = (idx & 7) * 4;
    float4 o;
    o.x = Cs[n * 33 + j4 + 0] + bias[j0 + j4 + 0];
    o.y = Cs[n * 33 + j4 + 1] + bias[j0 + j4 + 1];
    o.z = Cs[n * 33 + j4 + 2] + bias[j0 + j4 + 2];
    o.w = Cs[n * 33 + j4 + 3] + bias[j0 + j4 + 3];
    *(float4*)&Cc[(size_t)(n0 + n) * C_ + j0 + j4] = o;
  }
}

extern "C" void kernel_launch(void* const* d_in, const int* in_sizes, int n_in,
                              void* d_out, int out_size, void* d_ws,
                              size_t ws_size, hipStream_t stream) {
  const float* x = (const float*)d_in[0];
  const float* eh = (const float*)d_in[1];
  const int* shot_starts = (const int*)d_in[2];
  const int* shot_ends = (const int*)d_in[3];
  const float* Wq = (const float*)d_in[4];
  const float* bq = (const float*)d_in[5];
  const float* Wk = (const float*)d_in[6];
  const float* bk = (const float*)d_in[7];
  const float* Wv = (const float*)d_in[8];
  const float* bv = (const float*)d_in[9];
  const float* Wp = (const float*)d_in[10];
  const float* bp = (const float*)d_in[11];
  float* out = (float*)d_out;

  float* ws = (float*)d_ws;
  float* qkT = ws + WS_QKT;
  float* qb = ws + WS_QB;
  float* ms = ws + WS_MS;
  float* li = ws + WS_LI;
  float* att = ws + WS_ATT;
  float* wsum = ws + WS_WSUM;
  float* attnout = ws + WS_ATTNOUT;

  hipMemsetAsync(wsum, 0, (size_t)1024 * H_ * C_ * sizeof(float), stream);
  k_prep<<<dim3(8, 8), 256, 0, stream>>>(x, Wq, bq, Wk, bk, qkT, qb);
  k_att<<<dim3(T_ / 64, B_), 256, 0, stream>>>(eh, qkT, qb, att);
  k_stats<<<B_ * S_, 256, 0, stream>>>(att, shot_starts, shot_ends, ms, li);
  k_wsum_win<<<dim3(T_ / 64, B_), 256, 0, stream>>>(eh, att, ms, li,
                                                    shot_starts, shot_ends,
                                                    wsum);
  k_gemm<<<dim3(16, 16), 256, 0, stream>>>(wsum, H_ * C_, C_, Wv, bv, attnout);
  k_gemm<<<dim3(16, 16), 256, 0, stream>>>(attnout, C_, 0, Wp, bp, out);
}

// Round 4
// 373.850 us; speedup vs baseline: 1.2508x; 1.2508x over previous
//
#include <hip/hip_runtime.h>
#include <cstdint>
#include <cstddef>

#define B_ 16
#define S_ 64
#define T_ 4096
#define C_ 512
#define H_ 8

// ws layout (float offsets):
#define WS_QKT     0         // [512][8]
#define WS_QB      4096      // [8]
#define WS_QH      4104      // [512]
#define WS_MS      4616      // [1024][8]
#define WS_LI      12808     // [1024][8]
#define WS_CNT     21000     // [16] int
#define WS_CSEG    21016     // [16][128] int
#define WS_CIDX    23064     // [16][128] int
#define WS_CMUL    25112     // [16][128] int
#define WS_ATT     28672     // [B][H][T]      (524288)
#define WS_WSUM    552960    // [1024][8][512] (4194304)
#define WS_ATTNOUT 4747264   // [1024][512]    (524288)
// end 5271552 floats ~= 20.1 MB

// P1: qh[r] = (Wq@x + bq)[r] / 8.  grid 16, block 256 (32 rows/block).
__global__ void k_prep1(const float* __restrict__ x, const float* __restrict__ Wq,
                        const float* __restrict__ bq, float* __restrict__ qh_g) {
  __shared__ float xs[C_];
  __shared__ float red[256];
  int tid = threadIdx.x;
  xs[tid] = x[tid];
  xs[tid + 256] = x[tid + 256];
  __syncthreads();
  int r0 = blockIdx.x * 32;
  int rl = tid >> 3, sub = tid & 7;
  int r = r0 + rl;
  const float* wr = Wq + (size_t)r * C_ + sub * 64;
  const float* xp = xs + sub * 64;
  float s = 0.f;
#pragma unroll
  for (int i = 0; i < 64; i += 4) {
    float4 w = *(const float4*)(wr + i);
    s += w.x * xp[i] + w.y * xp[i + 1] + w.z * xp[i + 2] + w.w * xp[i + 3];
  }
  red[tid] = s;
  __syncthreads();
  if (sub == 0) {
    float tot = bq[r];
#pragma unroll
    for (int i = 0; i < 8; ++i) tot += red[rl * 8 + i];
    qh_g[r] = tot * 0.125f;
  }
}

// P2: qkT[c][h] = sum_d qh[h*64+d]*Wk[h*64+d][c]; qb[h] = sum_d qh*bk.
// grid 8 (h), block 256. Coalesced over c per d.
__global__ void k_prep2(const float* __restrict__ qh_g,
                        const float* __restrict__ Wk,
                        const float* __restrict__ bk, float* __restrict__ qkT,
                        float* __restrict__ qb) {
  __shared__ float qhs[64];
  int tid = threadIdx.x;
  int h = blockIdx.x;
  if (tid < 64) qhs[tid] = qh_g[h * 64 + tid];
  __syncthreads();
  int c0 = tid, c1 = tid + 256;
  float s0 = 0.f, s1 = 0.f;
#pragma unroll 8
  for (int d = 0; d < 64; ++d) {
    const float* row = Wk + (size_t)(h * 64 + d) * C_;
    float q = qhs[d];
    s0 += q * row[c0];
    s1 += q * row[c1];
  }
  qkT[c0 * 8 + h] = s0;
  qkT[c1 * 8 + h] = s1;
  if (tid < 64) {
    float w = qhs[tid] * bk[h * 64 + tid];
#pragma unroll
    for (int off = 32; off > 0; off >>= 1) w += __shfl_down(w, off, 64);
    if (tid == 0) qb[h] = w;
  }
}

// K2: att[b][h][t] = qb[h] + sum_c qkT[c][h]*eh[b][c][t]
// grid (64, 16), block 256: 64 t per block, 4 c-slices of 128 (R2 form).
__global__ __launch_bounds__(256, 4) void k_att(
    const float* __restrict__ eh, const float* __restrict__ qkT,
    const float* __restrict__ qb, float* __restrict__ att) {
  __shared__ float qks[C_ * 8];       // 16 KB
  __shared__ float part[4 * 8 * 64];  // 8 KB [cg][h][tl]
  int tid = threadIdx.x;
  int tl = tid & 63, cg = tid >> 6;
  int b = blockIdx.y;
  int t0 = blockIdx.x * 64;
#pragma unroll
  for (int i = 0; i < 16; ++i) qks[tid + i * 256] = qkT[tid + i * 256];
  __syncthreads();
  const float* ehp = eh + ((size_t)b * C_ + (size_t)cg * 128) * T_ + t0 + tl;
  float acc[8];
#pragma unroll
  for (int h = 0; h < 8; ++h) acc[h] = 0.f;
#pragma unroll 4
  for (int j = 0; j < 128; ++j) {
    float e = ehp[(size_t)j * T_];
    const float4 q0 = *(const float4*)&qks[(cg * 128 + j) * 8];
    const float4 q1 = *(const float4*)&qks[(cg * 128 + j) * 8 + 4];
    acc[0] += q0.x * e; acc[1] += q0.y * e; acc[2] += q0.z * e; acc[3] += q0.w * e;
    acc[4] += q1.x * e; acc[5] += q1.y * e; acc[6] += q1.z * e; acc[7] += q1.w * e;
  }
#pragma unroll
  for (int h = 0; h < 8; ++h) part[(cg * 8 + h) * 64 + tl] = acc[h];
  __syncthreads();
#pragma unroll
  for (int i = 0; i < 2; ++i) {
    int idx = tid + i * 256;
    int h = idx >> 6, tt = idx & 63;
    float v = part[(0 * 8 + h) * 64 + tt] + part[(1 * 8 + h) * 64 + tt] +
              part[(2 * 8 + h) * 64 + tt] + part[(3 * 8 + h) * 64 + tt] + qb[h];
    att[((size_t)b * H_ + h) * T_ + t0 + tt] = v;
  }
}

// K3: softmax stats per (n, h): ms = max, li = 1/sum(exp). grid 1024.
__global__ void k_stats(const float* __restrict__ att,
                        const int* __restrict__ starts,
                        const int* __restrict__ ends, float* __restrict__ ms,
                        float* __restrict__ li) {
  int tid = threadIdx.x;
  int n = blockIdx.x;
  int b = n >> 6;
  int start = starts[n], end = ends[n];
  int h = tid >> 5, tl = tid & 31;
  const float* ah = att + ((size_t)b * H_ + h) * T_;
  float mloc = -3.0e38f;
  for (int t = start + tl; t < end; t += 32) mloc = fmaxf(mloc, ah[t]);
#pragma unroll
  for (int off = 16; off > 0; off >>= 1)
    mloc = fmaxf(mloc, __shfl_xor(mloc, off, 32));
  float lloc = 0.f;
  for (int t = start + tl; t < end; t += 32) lloc += __expf(ah[t] - mloc);
#pragma unroll
  for (int off = 16; off > 0; off >>= 1) lloc += __shfl_xor(lloc, off, 32);
  if (tl == 0) { ms[n * 8 + h] = mloc; li[n * 8 + h] = 1.f / lloc; }
}

// K4: build chunk map. grid 16, block 64 (one wave).
// Segment s split into nch = ceil((end - (start&~31))/128) chunks with
// 128-float-aligned interior boundaries. Prefix-sum -> block slots.
__global__ void k_map(const int* __restrict__ starts,
                      const int* __restrict__ ends, int* __restrict__ cnt,
                      int* __restrict__ cseg, int* __restrict__ cidx,
                      int* __restrict__ cmul) {
  int b = blockIdx.x;
  int s = threadIdx.x;
  int st = starts[b * 64 + s], en = ends[b * 64 + s];
  int cbase = st & ~31;
  int nch = (en - cbase + 127) >> 7;
  int x = nch;
#pragma unroll
  for (int off = 1; off < 64; off <<= 1) {
    int y = __shfl_up(x, off, 64);
    if (s >= off) x += y;
  }
  int pre = x - nch;
  for (int k = 0; k < nch; ++k) {
    cseg[b * 128 + pre + k] = s;
    cidx[b * 128 + pre + k] = k;
    cmul[b * 128 + pre + k] = (nch > 1) ? 1 : 0;
  }
  if (s == 63) cnt[b] = x;
}

// K5: wsum[n][h][c] = sum_{t in seg} p[h][t]*eh[b][c][t], one block per
// <=128-t chunk. grid (128, 16), block 256; excess blocks exit.
// Single-chunk segments: plain store. Multi-chunk: atomicAdd (wsum zeroed).
__global__ __launch_bounds__(256, 4) void k_wsum(
    const float* __restrict__ eh, const float* __restrict__ att,
    const float* __restrict__ ms, const float* __restrict__ li,
    const int* __restrict__ starts, const int* __restrict__ ends,
    const int* __restrict__ cnt, const int* __restrict__ cseg,
    const int* __restrict__ cidx, const int* __restrict__ cmul,
    float* __restrict__ wsum) {
  __shared__ float pl[8 * 136];
  int b = blockIdx.y;
  int i = blockIdx.x;
  if (i >= cnt[b]) return;
  int tid = threadIdx.x;
  int s = cseg[b * 128 + i];
  int k = cidx[b * 128 + i];
  int mul = cmul[b * 128 + i];
  int n = b * 64 + s;
  int st = starts[n], en = ends[n];
  int cbase = st & ~31;
  int t_lo = cbase + k * 128;
  if (st > t_lo) t_lo = st;
  int t_hi = cbase + (k + 1) * 128;
  if (en < t_hi) t_hi = en;
  int base = t_lo & ~3;

  // stage p[h][t-base] (stride 136), zero outside [t_lo, t_hi)
  int h = tid >> 5, l32 = tid & 31;
  float msn = ms[n * 8 + h], lin = li[n * 8 + h];
  const float* ah = att + ((size_t)b * H_ + h) * T_;
  for (int j = l32; j < 136; j += 32) {
    int t = base + j;
    float pv = 0.f;
    if (t >= t_lo && t < t_hi) pv = __expf(ah[t] - msn) * lin;
    pl[h * 136 + j] = pv;
  }
  __syncthreads();

  float acc0[8], acc1[8];
#pragma unroll
  for (int hh = 0; hh < 8; ++hh) { acc0[hh] = 0.f; acc1[hh] = 0.f; }
  const float* e0p = eh + ((size_t)b * C_ + tid) * T_ + base;
  const float* e1p = e0p + (size_t)256 * T_;
  int jmax = t_hi - base;
  int jv = jmax & ~3;
#pragma unroll 2
  for (int j = 0; j < jv; j += 4) {
    float4 e0 = *(const float4*)(e0p + j);
    float4 e1 = *(const float4*)(e1p + j);
#pragma unroll
    for (int hh = 0; hh < 8; ++hh) {
      const float4 p = *(const float4*)&pl[hh * 136 + j];
      acc0[hh] += p.x * e0.x + p.y * e0.y + p.z * e0.z + p.w * e0.w;
      acc1[hh] += p.x * e1.x + p.y * e1.y + p.z * e1.z + p.w * e1.w;
    }
  }
  for (int j = jv; j < jmax; ++j) {
    float e0 = e0p[j], e1 = e1p[j];
#pragma unroll
    for (int hh = 0; hh < 8; ++hh) {
      float p = pl[hh * 136 + j];
      acc0[hh] += p * e0;
      acc1[hh] += p * e1;
    }
  }
  float* wp = wsum + (size_t)n * (H_ * C_);
  if (!mul) {
#pragma unroll
    for (int hh = 0; hh < 8; ++hh) {
      wp[hh * C_ + tid] = acc0[hh];
      wp[hh * C_ + 256 + tid] = acc1[hh];
    }
  } else {
#pragma unroll
    for (int hh = 0; hh < 8; ++hh) {
      atomicAdd(&wp[hh * C_ + tid], acc0[hh]);
      atomicAdd(&wp[hh * C_ + 256 + tid], acc1[hh]);
    }
  }
}

// K6/K7: C[n][y*64+j] = sum_k A[n*aRow + y*aColPerY + k]*Bm[(y*64+j)*512+k]
//        + bias[y*64+j].  32x64 tile, 256 threads, 2x4 per thread (R2 form).
__global__ __launch_bounds__(256, 4) void k_gemm(
    const float* __restrict__ A, long aRow, long aColPerY,
    const float* __restrict__ Bm, const float* __restrict__ bias,
    float* __restrict__ Cc) {
  __shared__ float As[32 * 36];
  __shared__ float Bs[64 * 36];
  int tid = threadIdx.x;
  int n0 = blockIdx.x * 32;
  int y = blockIdx.y;
  const float* Abase = A + (size_t)n0 * aRow + (size_t)y * aColPerY;
  const float* Bbase = Bm + (size_t)(y * 64) * C_;
  int tx = tid & 15, ty = tid >> 4;
  float acc[2][4];
#pragma unroll
  for (int a = 0; a < 2; ++a)
#pragma unroll
    for (int bb = 0; bb < 4; ++bb) acc[a][bb] = 0.f;
  for (int k0 = 0; k0 < 512; k0 += 32) {
#pragma unroll
    for (int i = 0; i < 4; ++i) {
      int idx = tid + i * 256;
      int r = idx >> 5, cc = idx & 31;
      As[r * 36 + cc] = Abase[(size_t)r * aRow + k0 + cc];
    }
#pragma unroll
    for (int i = 0; i < 8; ++i) {
      int idx = tid + i * 256;
      int r = idx >> 5, cc = idx & 31;
      Bs[r * 36 + cc] = Bbase[(size_t)r * C_ + k0 + cc];
    }
    __syncthreads();
#pragma unroll
    for (int k = 0; k < 32; k += 4) {
      const float4 a0 = *(const float4*)&As[(ty * 2 + 0) * 36 + k];
      const float4 a1 = *(const float4*)&As[(ty * 2 + 1) * 36 + k];
#pragma unroll
      for (int bb = 0; bb < 4; ++bb) {
        const float4 bv = *(const float4*)&Bs[(tx * 4 + bb) * 36 + k];
        acc[0][bb] += a0.x * bv.x + a0.y * bv.y + a0.z * bv.z + a0.w * bv.w;
        acc[1][bb] += a1.x * bv.x + a1.y * bv.y + a1.z * bv.z + a1.w * bv.w;
      }
    }
    __syncthreads();
  }
#pragma unroll
  for (int a = 0; a < 2; ++a) {
    int nn = n0 + ty * 2 + a;
    float4 o;
    o.x = acc[a][0] + bias[y * 64 + tx * 4 + 0];
    o.y = acc[a][1] + bias[y * 64 + tx * 4 + 1];
    o.z = acc[a][2] + bias[y * 64 + tx * 4 + 2];
    o.w = acc[a][3] + bias[y * 64 + tx * 4 + 3];
    *(float4*)&Cc[(size_t)nn * C_ + y * 64 + tx * 4] = o;
  }
}

extern "C" void kernel_launch(void* const* d_in, const int* in_sizes, int n_in,
                              void* d_out, int out_size, void* d_ws,
                              size_t ws_size, hipStream_t stream) {
  const float* x = (const float*)d_in[0];
  const float* eh = (const float*)d_in[1];
  const int* shot_starts = (const int*)d_in[2];
  const int* shot_ends = (const int*)d_in[3];
  const float* Wq = (const float*)d_in[4];
  const float* bq = (const float*)d_in[5];
  const float* Wk = (const float*)d_in[6];
  const float* bk = (const float*)d_in[7];
  const float* Wv = (const float*)d_in[8];
  const float* bv = (const float*)d_in[9];
  const float* Wp = (const float*)d_in[10];
  const float* bp = (const float*)d_in[11];
  float* out = (float*)d_out;

  float* ws = (float*)d_ws;
  float* qkT = ws + WS_QKT;
  float* qb = ws + WS_QB;
  float* qh = ws + WS_QH;
  float* ms = ws + WS_MS;
  float* li = ws + WS_LI;
  int* cnt = (int*)(ws + WS_CNT);
  int* cseg = (int*)(ws + WS_CSEG);
  int* cidx = (int*)(ws + WS_CIDX);
  int* cmul = (int*)(ws + WS_CMUL);
  float* att = ws + WS_ATT;
  float* wsum = ws + WS_WSUM;
  float* attnout = ws + WS_ATTNOUT;

  hipMemsetAsync(wsum, 0, (size_t)1024 * H_ * C_ * sizeof(float), stream);
  k_prep1<<<16, 256, 0, stream>>>(x, Wq, bq, qh);
  k_prep2<<<8, 256, 0, stream>>>(qh, Wk, bk, qkT, qb);
  k_att<<<dim3(T_ / 64, B_), 256, 0, stream>>>(eh, qkT, qb, att);
  k_stats<<<B_ * S_, 256, 0, stream>>>(att, shot_starts, shot_ends, ms, li);
  k_map<<<B_, 64, 0, stream>>>(shot_starts, shot_ends, cnt, cseg, cidx, cmul);
  k_wsum<<<dim3(128, B_), 256, 0, stream>>>(eh, att, ms, li, shot_starts,
                                            shot_ends, cnt, cseg, cidx, cmul,
                                            wsum);
  k_gemm<<<dim3(32, 8), 256, 0, stream>>>(wsum, (long)(H_ * C_), (long)C_, Wv,
                                          bv, attnout);
  k_gemm<<<dim3(32, 8), 256, 0, stream>>>(attnout, (long)C_, 0L, Wp, bp, out);
}